// Round 2
// baseline (271.661 us; speedup 1.0000x reference)
//
#include <hip/hip_runtime.h>
#include <hip/hip_fp16.h>

// LogicLayer: out[b,n] = C0[n] + C1[n]*a + C2[n]*b + C3[n]*a*b
// where a = x[b, idx_a[n]], b = x[b, idx_b[n]] and C0..C3 are linear
// combos of softmax(w[n]). Coeffs precomputed into d_ws.
// logic_kernel: one block per batch row; row staged in LDS as fp16
// (32 KB -> LDS no longer occupancy limiter); fixed trip counts fully
// unrolled for load pipelining.

#define IN_N   16384
#define OUT_N  16384
#define TPB    512
#define GITERS (OUT_N / 4 / TPB)   // 8
#define SITERS (IN_N / 4 / TPB)    // 8

__global__ __launch_bounds__(256) void coeff_kernel(const float* __restrict__ w,
                                                    float4* __restrict__ coeff,
                                                    int nout) {
    int n = blockIdx.x * blockDim.x + threadIdx.x;
    if (n >= nout) return;
    const float4* wn4 = (const float4*)(w + (size_t)n * 16);
    float p[16];
    float4 w0 = wn4[0], w1 = wn4[1], w2 = wn4[2], w3 = wn4[3];
    p[0] = w0.x; p[1] = w0.y; p[2] = w0.z; p[3] = w0.w;
    p[4] = w1.x; p[5] = w1.y; p[6] = w1.z; p[7] = w1.w;
    p[8] = w2.x; p[9] = w2.y; p[10] = w2.z; p[11] = w2.w;
    p[12] = w3.x; p[13] = w3.y; p[14] = w3.z; p[15] = w3.w;
    float m = -1e30f;
#pragma unroll
    for (int i = 0; i < 16; ++i) m = fmaxf(m, p[i]);
    float s = 0.f;
#pragma unroll
    for (int i = 0; i < 16; ++i) { p[i] = __expf(p[i] - m); s += p[i]; }
    float inv = 1.f / s;
#pragma unroll
    for (int i = 0; i < 16; ++i) p[i] *= inv;
    // gates: 0, ab, a-ab, a, b-ab, b, a+b-2ab, a+b-ab,
    //        1-a-b+ab, 1-a-b+2ab, 1-b, 1-b+ab, 1-a, 1-a+ab, 1-ab, 1
    float c0 = p[8] + p[9] + p[10] + p[11] + p[12] + p[13] + p[14] + p[15];
    float c1 = p[2] + p[3] + p[6] + p[7] - p[8] - p[9] - p[12] - p[13];
    float c2 = p[4] + p[5] + p[6] + p[7] - p[8] - p[9] - p[10] - p[11];
    float c3 = p[1] - p[2] - p[4] - 2.f * p[6] - p[7]
             + p[8] + 2.f * p[9] + p[11] + p[13] - p[14];
    coeff[n] = make_float4(c0, c1, c2, c3);
}

__global__ __launch_bounds__(TPB, 4) void logic_kernel(const float* __restrict__ x,
                                                       const int4* __restrict__ ia4,
                                                       const int4* __restrict__ ib4,
                                                       const float4* __restrict__ coeff,
                                                       float* __restrict__ out) {
    __shared__ __half row[IN_N];  // 32 KB fp16 row

    const int b = blockIdx.x;
    const int t = threadIdx.x;

    const float4* xr4 = (const float4*)(x + (size_t)b * IN_N);
    __half2* row2 = (__half2*)row;
#pragma unroll
    for (int k = 0; k < SITERS; ++k) {
        int j = t + k * TPB;
        float4 v = xr4[j];
        row2[2 * j]     = __floats2half2_rn(v.x, v.y);
        row2[2 * j + 1] = __floats2half2_rn(v.z, v.w);
    }
    __syncthreads();

    float4* outr4 = (float4*)(out + (size_t)b * OUT_N);
#pragma unroll
    for (int k = 0; k < GITERS; ++k) {
        int n4 = t + k * TPB;
        int4 ia = ia4[n4];
        int4 ib = ib4[n4];
        float4 c0 = coeff[4 * n4 + 0];
        float4 c1 = coeff[4 * n4 + 1];
        float4 c2 = coeff[4 * n4 + 2];
        float4 c3 = coeff[4 * n4 + 3];
        float a0 = __half2float(row[ia.x]);
        float a1 = __half2float(row[ia.y]);
        float a2 = __half2float(row[ia.z]);
        float a3 = __half2float(row[ia.w]);
        float b0 = __half2float(row[ib.x]);
        float b1 = __half2float(row[ib.y]);
        float b2 = __half2float(row[ib.z]);
        float b3 = __half2float(row[ib.w]);
        float4 o;
        o.x = fmaf(a0, fmaf(c0.w, b0, c0.y), fmaf(c0.z, b0, c0.x));
        o.y = fmaf(a1, fmaf(c1.w, b1, c1.y), fmaf(c1.z, b1, c1.x));
        o.z = fmaf(a2, fmaf(c2.w, b2, c2.y), fmaf(c2.z, b2, c2.x));
        o.w = fmaf(a3, fmaf(c3.w, b3, c3.y), fmaf(c3.z, b3, c3.x));
        outr4[n4] = o;
    }
}

extern "C" void kernel_launch(void* const* d_in, const int* in_sizes, int n_in,
                              void* d_out, int out_size, void* d_ws, size_t ws_size,
                              hipStream_t stream) {
    const float* x = (const float*)d_in[0];       // (B, IN) fp32
    const float* w = (const float*)d_in[1];       // (OUT, 16) fp32
    const int* idx_a = (const int*)d_in[2];       // (OUT,) int32
    const int* idx_b = (const int*)d_in[3];       // (OUT,) int32

    const int nout = in_sizes[2];                 // 16384
    const int batch = in_sizes[0] / IN_N;         // 2048

    float4* coeff = (float4*)d_ws;                // nout * 16 B = 256 KB

    coeff_kernel<<<(nout + 255) / 256, 256, 0, stream>>>(w, coeff, nout);
    logic_kernel<<<batch, TPB, 0, stream>>>(x, (const int4*)idx_a, (const int4*)idx_b,
                                            coeff, (float*)d_out);
}

// Round 3
// 267.686 us; speedup vs baseline: 1.0149x; 1.0149x over previous
//
#include <hip/hip_runtime.h>
#include <hip/hip_fp16.h>

// LogicLayer: out[b,n] = C0[n] + C1[n]*a + C2[n]*b + C3[n]*a*b,
//   a = x[b, idx_a[n]], b = x[b, idx_b[n]], C = linear combos of softmax(w[n]).
//
// R3 structure:
//  - prep_kernel: per-neuron coeffs packed to fp16 (uint2/neuron) + idx packed
//    to ushort pairs (uint4 per neuron-quad) in d_ws.
//  - logic_kernel: 1024 threads, 8 batch rows per block, grid=256 (1/CU).
//    idx+coeff held in registers for all 8 rows (48 VGPRs).
//    fp32 row double-buffered in LDS (2x64KB) via async global_load_lds;
//    stage(r+1) issued before gather(r) -> stage/gather overlap, barrier's
//    vmcnt drain doubles as the row-ready sync.

#define IN_N   16384
#define OUT_N  16384
#define TPB    1024
#define ROWS   8
#define GITERS (OUT_N / 4 / TPB)      // 4 neuron-quads per thread
#define CHUNKS (IN_N * 4 / TPB / 16)  // 4 x 16B global_load_lds per thread per row

typedef unsigned int u32;
typedef const __attribute__((address_space(1))) u32* gas_ptr;
typedef __attribute__((address_space(3))) u32* las_ptr;

__global__ __launch_bounds__(256) void prep_kernel(const float* __restrict__ w,
                                                   const int* __restrict__ idx_a,
                                                   const int* __restrict__ idx_b,
                                                   uint2* __restrict__ pcoef,
                                                   uint4* __restrict__ pidx,
                                                   int nout) {
    int n = blockIdx.x * blockDim.x + threadIdx.x;
    if (n < nout) {
        const float4* wn4 = (const float4*)(w + (size_t)n * 16);
        float p[16];
        float4 w0 = wn4[0], w1 = wn4[1], w2 = wn4[2], w3 = wn4[3];
        p[0] = w0.x; p[1] = w0.y; p[2] = w0.z; p[3] = w0.w;
        p[4] = w1.x; p[5] = w1.y; p[6] = w1.z; p[7] = w1.w;
        p[8] = w2.x; p[9] = w2.y; p[10] = w2.z; p[11] = w2.w;
        p[12] = w3.x; p[13] = w3.y; p[14] = w3.z; p[15] = w3.w;
        float m = -1e30f;
#pragma unroll
        for (int i = 0; i < 16; ++i) m = fmaxf(m, p[i]);
        float s = 0.f;
#pragma unroll
        for (int i = 0; i < 16; ++i) { p[i] = __expf(p[i] - m); s += p[i]; }
        float inv = 1.f / s;
#pragma unroll
        for (int i = 0; i < 16; ++i) p[i] *= inv;
        // gates: 0, ab, a-ab, a, b-ab, b, a+b-2ab, a+b-ab,
        //        1-a-b+ab, 1-a-b+2ab, 1-b, 1-b+ab, 1-a, 1-a+ab, 1-ab, 1
        float c0 = p[8] + p[9] + p[10] + p[11] + p[12] + p[13] + p[14] + p[15];
        float c1 = p[2] + p[3] + p[6] + p[7] - p[8] - p[9] - p[12] - p[13];
        float c2 = p[4] + p[5] + p[6] + p[7] - p[8] - p[9] - p[10] - p[11];
        float c3 = p[1] - p[2] - p[4] - 2.f * p[6] - p[7]
                 + p[8] + 2.f * p[9] + p[11] + p[13] - p[14];
        __half2 h01 = __floats2half2_rn(c0, c1);
        __half2 h23 = __floats2half2_rn(c2, c3);
        uint2 r;
        r.x = __builtin_bit_cast(u32, h01);
        r.y = __builtin_bit_cast(u32, h23);
        pcoef[n] = r;
    }
    if (n < nout / 4) {
        int4 a = ((const int4*)idx_a)[n];
        int4 b = ((const int4*)idx_b)[n];
        uint4 r;
        r.x = (u32)a.x | ((u32)a.y << 16);
        r.y = (u32)a.z | ((u32)a.w << 16);
        r.z = (u32)b.x | ((u32)b.y << 16);
        r.w = (u32)b.z | ((u32)b.w << 16);
        pidx[n] = r;
    }
}

__device__ __forceinline__ void stage_row(const float* __restrict__ gsrc,
                                          float* ldst, int t) {
#pragma unroll
    for (int j = 0; j < CHUNKS; ++j) {
        int c = (j * TPB + t) * 4;  // float index, 16B per thread-chunk
        __builtin_amdgcn_global_load_lds((gas_ptr)(const void*)(gsrc + c),
                                         (las_ptr)(void*)(ldst + c),
                                         16, 0, 0);
    }
}

__device__ __forceinline__ float2 h2f(u32 bits) {
    return __half22float2(__builtin_bit_cast(__half2, bits));
}

__global__ __launch_bounds__(TPB) void logic_kernel(const float* __restrict__ x,
                                                    const uint4* __restrict__ pidx,
                                                    const uint4* __restrict__ pcoef,
                                                    float* __restrict__ out,
                                                    int batch) {
    __shared__ float row[2][IN_N];  // 2 x 64 KB double buffer

    const int t = threadIdx.x;
    const int b0 = blockIdx.x * ROWS;

    // Preload idx + coeffs for this thread's 4 neuron-quads into registers.
    uint4 id[GITERS];       // packed ushort indices: {a01,a23,b01,b23}
    uint4 pcA[GITERS];      // coeffs (fp16) neurons 0,1 of quad
    uint4 pcB[GITERS];      // coeffs (fp16) neurons 2,3 of quad
#pragma unroll
    for (int k = 0; k < GITERS; ++k) {
        int q = k * TPB + t;
        id[k]  = pidx[q];
        pcA[k] = pcoef[2 * q + 0];
        pcB[k] = pcoef[2 * q + 1];
    }

    stage_row(x + (size_t)b0 * IN_N, row[0], t);
    __syncthreads();

    for (int r = 0; r < ROWS; ++r) {
        const int b = b0 + r;
        if (r + 1 < ROWS)
            stage_row(x + (size_t)(b + 1) * IN_N, row[(r + 1) & 1], t);

        const float* rbuf = row[r & 1];
        float4* outr4 = (float4*)(out + (size_t)b * OUT_N);
#pragma unroll
        for (int k = 0; k < GITERS; ++k) {
            u32 a01 = id[k].x, a23 = id[k].y, b01 = id[k].z, b23 = id[k].w;
            float a0 = rbuf[a01 & 0xffff], a1 = rbuf[a01 >> 16];
            float a2 = rbuf[a23 & 0xffff], a3 = rbuf[a23 >> 16];
            float v0 = rbuf[b01 & 0xffff], v1 = rbuf[b01 >> 16];
            float v2 = rbuf[b23 & 0xffff], v3 = rbuf[b23 >> 16];
            float2 c01_0 = h2f(pcA[k].x), c23_0 = h2f(pcA[k].y);
            float2 c01_1 = h2f(pcA[k].z), c23_1 = h2f(pcA[k].w);
            float2 c01_2 = h2f(pcB[k].x), c23_2 = h2f(pcB[k].y);
            float2 c01_3 = h2f(pcB[k].z), c23_3 = h2f(pcB[k].w);
            float4 o;
            o.x = fmaf(a0, fmaf(c23_0.y, v0, c01_0.y), fmaf(c23_0.x, v0, c01_0.x));
            o.y = fmaf(a1, fmaf(c23_1.y, v1, c01_1.y), fmaf(c23_1.x, v1, c01_1.x));
            o.z = fmaf(a2, fmaf(c23_2.y, v2, c01_2.y), fmaf(c23_2.x, v2, c01_2.x));
            o.w = fmaf(a3, fmaf(c23_3.y, v3, c01_3.y), fmaf(c23_3.x, v3, c01_3.x));
            outr4[k * TPB + t] = o;
        }
        __syncthreads();  // vmcnt drain = stage(r+1) complete; buffers safe
    }
}

extern "C" void kernel_launch(void* const* d_in, const int* in_sizes, int n_in,
                              void* d_out, int out_size, void* d_ws, size_t ws_size,
                              hipStream_t stream) {
    const float* x = (const float*)d_in[0];       // (B, IN) fp32
    const float* w = (const float*)d_in[1];       // (OUT, 16) fp32
    const int* idx_a = (const int*)d_in[2];       // (OUT,) int32
    const int* idx_b = (const int*)d_in[3];       // (OUT,) int32

    const int nout = in_sizes[2];                 // 16384
    const int batch = in_sizes[0] / IN_N;         // 2048

    uint2* pcoef = (uint2*)d_ws;                              // 16384*8B = 128 KB
    uint4* pidx  = (uint4*)((char*)d_ws + (size_t)nout * 8);  // 4096*16B = 64 KB

    prep_kernel<<<(nout + 255) / 256, 256, 0, stream>>>(w, idx_a, idx_b,
                                                        pcoef, pidx, nout);
    logic_kernel<<<batch / ROWS, TPB, 0, stream>>>(x, pidx, (const uint4*)pcoef,
                                                   (float*)d_out, batch);
}

// Round 4
// 241.072 us; speedup vs baseline: 1.1269x; 1.1104x over previous
//
#include <hip/hip_runtime.h>
#include <hip/hip_fp16.h>

// LogicLayer: out[b,n] = C0[n] + C1[n]*a + C2[n]*b + C3[n]*a*b,
//   a = x[b, idx_a[n]], b = x[b, idx_b[n]], C = linear combos of softmax(w[n]).
//
// R4: the bottleneck is the scalar LDS gather pipe (~1 elem/cyc/CU invariant
// across R1-R3). Amortize: stage 4 batch rows interleaved as fp16 so ONE
// ds_read_b64 per index serves 4 rows. 128 KB LDS, 1 block/CU, grid=512.

#define IN_N   16384
#define OUT_N  16384
#define TPB    1024
#define ROWS   4
#define GITERS (OUT_N / 4 / TPB)   // 4 neuron-quads per thread
#define SGRP   (IN_N / 4 / TPB)    // 4 column-groups of 4 per thread

typedef unsigned int u32;

__global__ __launch_bounds__(256) void prep_kernel(const float* __restrict__ w,
                                                   const int* __restrict__ idx_a,
                                                   const int* __restrict__ idx_b,
                                                   uint2* __restrict__ pcoef,
                                                   uint4* __restrict__ pidx,
                                                   int nout) {
    int n = blockIdx.x * blockDim.x + threadIdx.x;
    if (n < nout) {
        const float4* wn4 = (const float4*)(w + (size_t)n * 16);
        float p[16];
        float4 w0 = wn4[0], w1 = wn4[1], w2 = wn4[2], w3 = wn4[3];
        p[0] = w0.x; p[1] = w0.y; p[2] = w0.z; p[3] = w0.w;
        p[4] = w1.x; p[5] = w1.y; p[6] = w1.z; p[7] = w1.w;
        p[8] = w2.x; p[9] = w2.y; p[10] = w2.z; p[11] = w2.w;
        p[12] = w3.x; p[13] = w3.y; p[14] = w3.z; p[15] = w3.w;
        float m = -1e30f;
#pragma unroll
        for (int i = 0; i < 16; ++i) m = fmaxf(m, p[i]);
        float s = 0.f;
#pragma unroll
        for (int i = 0; i < 16; ++i) { p[i] = __expf(p[i] - m); s += p[i]; }
        float inv = 1.f / s;
#pragma unroll
        for (int i = 0; i < 16; ++i) p[i] *= inv;
        // gates: 0, ab, a-ab, a, b-ab, b, a+b-2ab, a+b-ab,
        //        1-a-b+ab, 1-a-b+2ab, 1-b, 1-b+ab, 1-a, 1-a+ab, 1-ab, 1
        float c0 = p[8] + p[9] + p[10] + p[11] + p[12] + p[13] + p[14] + p[15];
        float c1 = p[2] + p[3] + p[6] + p[7] - p[8] - p[9] - p[12] - p[13];
        float c2 = p[4] + p[5] + p[6] + p[7] - p[8] - p[9] - p[10] - p[11];
        float c3 = p[1] - p[2] - p[4] - 2.f * p[6] - p[7]
                 + p[8] + 2.f * p[9] + p[11] + p[13] - p[14];
        uint2 r;
        r.x = __builtin_bit_cast(u32, __floats2half2_rn(c0, c1));
        r.y = __builtin_bit_cast(u32, __floats2half2_rn(c2, c3));
        pcoef[n] = r;
    }
    if (n < nout / 4) {
        int4 a = ((const int4*)idx_a)[n];
        int4 b = ((const int4*)idx_b)[n];
        uint4 r;
        r.x = (u32)a.x | ((u32)a.y << 16);
        r.y = (u32)a.z | ((u32)a.w << 16);
        r.z = (u32)b.x | ((u32)b.y << 16);
        r.w = (u32)b.z | ((u32)b.w << 16);
        pidx[n] = r;
    }
}

__device__ __forceinline__ float2 h2f(u32 bits) {
    return __half22float2(__builtin_bit_cast(__half2, bits));
}
__device__ __forceinline__ u32 pkh(float a, float b) {
    return __builtin_bit_cast(u32, __floats2half2_rn(a, b));
}

// one neuron, 4 rows: a/b are uint2 {rows01, rows23} fp16; coeffs (c0,c1),(c2,c3)
__device__ __forceinline__ void neuron4(uint2 a, uint2 b, float2 c01, float2 c23,
                                        float& o0, float& o1, float& o2, float& o3) {
    float2 aL = h2f(a.x), aH = h2f(a.y);
    float2 bL = h2f(b.x), bH = h2f(b.y);
    o0 = fmaf(aL.x, fmaf(c23.y, bL.x, c01.y), fmaf(c23.x, bL.x, c01.x));
    o1 = fmaf(aL.y, fmaf(c23.y, bL.y, c01.y), fmaf(c23.x, bL.y, c01.x));
    o2 = fmaf(aH.x, fmaf(c23.y, bH.x, c01.y), fmaf(c23.x, bH.x, c01.x));
    o3 = fmaf(aH.y, fmaf(c23.y, bH.y, c01.y), fmaf(c23.x, bH.y, c01.x));
}

__global__ __launch_bounds__(TPB, 4) void logic_kernel(const float* __restrict__ x,
                                                       const uint4* __restrict__ pidx,
                                                       const uint4* __restrict__ pcoef,
                                                       float* __restrict__ out) {
    __shared__ uint2 cols[IN_N];  // 128 KB: cols[i] = 4 rows of column i, fp16

    const int t = threadIdx.x;
    const int b0 = blockIdx.x * ROWS;
    const float4* xr[ROWS];
#pragma unroll
    for (int r = 0; r < ROWS; ++r)
        xr[r] = (const float4*)(x + (size_t)(b0 + r) * IN_N);

    // Stage: 4 rows -> fp16 column-interleaved LDS.
#pragma unroll
    for (int g = 0; g < SGRP; ++g) {
        int c4 = g * TPB + t;      // float4 index
        float4 v0 = xr[0][c4];
        float4 v1 = xr[1][c4];
        float4 v2 = xr[2][c4];
        float4 v3 = xr[3][c4];
        uint4 q0, q1;
        q0.x = pkh(v0.x, v1.x); q0.y = pkh(v2.x, v3.x);
        q0.z = pkh(v0.y, v1.y); q0.w = pkh(v2.y, v3.y);
        q1.x = pkh(v0.z, v1.z); q1.y = pkh(v2.z, v3.z);
        q1.z = pkh(v0.w, v1.w); q1.w = pkh(v2.w, v3.w);
        uint4* dst = (uint4*)&cols[c4 * 4];
        dst[0] = q0;
        dst[1] = q1;
    }

    // Preload idx + coeffs (overlaps the barrier wait).
    uint4 id[GITERS], pA[GITERS], pB[GITERS];
#pragma unroll
    for (int k = 0; k < GITERS; ++k) {
        int q = k * TPB + t;
        id[k] = pidx[q];
        pA[k] = pcoef[2 * q + 0];
        pB[k] = pcoef[2 * q + 1];
    }

    __syncthreads();

    // Gather + compute: one ds_read_b64 per index serves 4 rows.
#pragma unroll
    for (int k = 0; k < GITERS; ++k) {
        int q = k * TPB + t;
        uint2 A0 = cols[id[k].x & 0xffff], A1 = cols[id[k].x >> 16];
        uint2 A2 = cols[id[k].y & 0xffff], A3 = cols[id[k].y >> 16];
        uint2 B0 = cols[id[k].z & 0xffff], B1 = cols[id[k].z >> 16];
        uint2 B2 = cols[id[k].w & 0xffff], B3 = cols[id[k].w >> 16];
        float4 o0, o1, o2, o3;  // one per row
        neuron4(A0, B0, h2f(pA[k].x), h2f(pA[k].y), o0.x, o1.x, o2.x, o3.x);
        neuron4(A1, B1, h2f(pA[k].z), h2f(pA[k].w), o0.y, o1.y, o2.y, o3.y);
        neuron4(A2, B2, h2f(pB[k].x), h2f(pB[k].y), o0.z, o1.z, o2.z, o3.z);
        neuron4(A3, B3, h2f(pB[k].z), h2f(pB[k].w), o0.w, o1.w, o2.w, o3.w);
        ((float4*)(out + (size_t)(b0 + 0) * OUT_N))[q] = o0;
        ((float4*)(out + (size_t)(b0 + 1) * OUT_N))[q] = o1;
        ((float4*)(out + (size_t)(b0 + 2) * OUT_N))[q] = o2;
        ((float4*)(out + (size_t)(b0 + 3) * OUT_N))[q] = o3;
    }
}

extern "C" void kernel_launch(void* const* d_in, const int* in_sizes, int n_in,
                              void* d_out, int out_size, void* d_ws, size_t ws_size,
                              hipStream_t stream) {
    const float* x = (const float*)d_in[0];       // (B, IN) fp32
    const float* w = (const float*)d_in[1];       // (OUT, 16) fp32
    const int* idx_a = (const int*)d_in[2];       // (OUT,) int32
    const int* idx_b = (const int*)d_in[3];       // (OUT,) int32

    const int nout = in_sizes[2];                 // 16384
    const int batch = in_sizes[0] / IN_N;         // 2048

    uint2* pcoef = (uint2*)d_ws;                              // 128 KB
    uint4* pidx  = (uint4*)((char*)d_ws + (size_t)nout * 8);  // 64 KB

    prep_kernel<<<(nout + 255) / 256, 256, 0, stream>>>(w, idx_a, idx_b,
                                                        pcoef, pidx, nout);
    logic_kernel<<<batch / ROWS, TPB, 0, stream>>>(x, pidx, (const uint4*)pcoef,
                                                   (float*)d_out);
}